// Round 3
// baseline (625.049 us; speedup 1.0000x reference)
//
#include <hip/hip_runtime.h>
#include <hip/hip_bf16.h>
#include <math.h>

#define B_SZ 32
#define T_SZ 2048
#define H_SZ 1024
#define U_SZ 1024

#define BM 64
#define BN 256
#define BK 64
#define UT_N (U_SZ / BN)   // 4
#define BM2 256            // big-tile GEMM row-block

typedef __attribute__((ext_vector_type(8))) short bf16x8;   // 8 bf16 = 4 VGPRs
typedef __attribute__((ext_vector_type(4))) float f32x4;    // mfma 16x16 accumulator

// fp32 -> bf16 round-to-nearest-even
__device__ __forceinline__ unsigned int f2bf(float f) {
  union { float f; unsigned int u; } x; x.f = f;
  unsigned int r = x.u + 0x7FFFu + ((x.u >> 16) & 1u);
  return r >> 16;
}

__device__ __forceinline__ float bf2f(unsigned int lo16) {
  union { unsigned int u; float f; } x; x.u = lo16 << 16; return x.f;
}

// async global -> LDS, 16 B per lane. LDS dest = wave-uniform base + lane*16.
__device__ __forceinline__ void async_cp16(const unsigned short* g, unsigned short* l) {
  __builtin_amdgcn_global_load_lds(
      (const __attribute__((address_space(1))) unsigned int*)g,
      (__attribute__((address_space(3))) unsigned int*)l, 16, 0, 0);
}

__device__ __forceinline__ float fast_tanh(float x) {
  const float e = __expf(x + x);
  return (e - 1.0f) * __builtin_amdgcn_rcpf(e + 1.0f);
}

// ---------------------------------------------------------------------------
// Fused prep: [0,cvtN): enc fp32->bf16 | [cvtN,+256): W2->W2t | [+256,+768): qq
// ---------------------------------------------------------------------------
__global__ __launch_bounds__(256) void k_prep(
    const float* __restrict__ enc, unsigned short* __restrict__ encb,
    const float* __restrict__ W2, unsigned short* __restrict__ W2t,
    const float* __restrict__ dec, const float* __restrict__ W1,
    const float* __restrict__ b1, const float* __restrict__ b2,
    float* __restrict__ qq, int cvtN)
{
  __shared__ char lds_raw[64 * 65 * 2];   // 8320 B, reused per branch
  const int bid = blockIdx.x;
  const int tid = threadIdx.x;

  if (bid < cvtN) {
    const size_t i = ((size_t)bid * 256 + tid) * 8;
    const float4 a = *(const float4*)(enc + i);
    const float4 b = *(const float4*)(enc + i + 4);
    uint4 o;
    o.x = f2bf(a.x) | (f2bf(a.y) << 16);
    o.y = f2bf(a.z) | (f2bf(a.w) << 16);
    o.z = f2bf(b.x) | (f2bf(b.y) << 16);
    o.w = f2bf(b.z) | (f2bf(b.w) << 16);
    *(uint4*)(encb + i) = o;
  } else if (bid < cvtN + 256) {
    unsigned short (*tile)[65] = (unsigned short(*)[65])lds_raw;
    const int idx = bid - cvtN;
    const int bu = idx & 15, bh = idx >> 4;
    const int tc = tid & 63, tr = tid >> 6;
    #pragma unroll
    for (int i = 0; i < 16; ++i) {
      const int hl = tr + i * 4;
      tile[tc][hl] = (unsigned short)f2bf(W2[(size_t)(bh * 64 + hl) * U_SZ + bu * 64 + tc]);
    }
    __syncthreads();
    #pragma unroll
    for (int i = 0; i < 16; ++i) {
      const int ul = tr + i * 4;
      W2t[(size_t)(bu * 64 + ul) * H_SZ + bh * 64 + tc] = tile[ul][tc];
    }
  } else {
    float (*red)[64] = (float(*)[64])lds_raw;
    const int idx = bid - (cvtN + 256);    // 0..511
    const int ul = tid & 63;
    const int hq = tid >> 6;
    const int u  = (idx & 15) * 64 + ul;
    const int b  = idx >> 4;
    const float* dh = dec + b * H_SZ + hq * 256;
    const float* w  = W1 + (size_t)(hq * 256) * U_SZ + u;
    float acc = 0.0f;
    #pragma unroll 8
    for (int h = 0; h < 256; ++h) acc += dh[h] * w[(size_t)h * U_SZ];
    red[hq][ul] = acc;
    __syncthreads();
    if (tid < 64) {
      const float s = red[0][ul] + red[1][ul] + red[2][ul] + red[3][ul];
      qq[b * U_SZ + u] = s + b1[u] + b2[u];
    }
  }
}

// ---------------------------------------------------------------------------
// Fast-path fused GEMM + tanh·V reduce, 4-phase pipelined K-loop.
// BM2=256 rows/block, 8 waves (2M x 4N), wave subtile 128x64, BK=64.
// 64 K-tiles (ut-major). Per tile: 4 phases, each {ds_read frags; issue 2-3
// prefetch loads for tile i+1; lgkmcnt(0); setprio(1); 16 MFMA; setprio(0);
// s_barrier}. vmcnt(0)+barrier once per tile at the boundary (loads issued
// >=1.5 phases earlier -> latency covered; no just-issued drain).
// Swizzle identical to verified baseline: chunk' = (chunk + row) & 7.
// ---------------------------------------------------------------------------
__global__ __launch_bounds__(512, 2) void k_gemm_score2(
    const unsigned short* __restrict__ encb,
    const unsigned short* __restrict__ W2t,
    const float* __restrict__ qq, const float* __restrict__ Vv,
    float* __restrict__ score)
{
  __shared__ unsigned short Al[2][BM2 * BK];   // 64 KB
  __shared__ unsigned short Bl[2][BN * BK];    // 64 KB

  const int tid  = threadIdx.x;
  const int wid  = tid >> 6;      // 0..7
  const int lane = tid & 63;
  const int quad = lane >> 4;
  const int l16  = lane & 15;
  const int wr   = wid >> 2;      // 0..1  (M side)
  const int wc   = wid & 3;       // 0..3  (N side)
  const int m0   = blockIdx.x * BM2;
  const int b    = m0 >> 11;      // 256 rows within one batch (2048 % 256 == 0)

  // staging addresses: j=0..3 A-slots (rows j*64..), j=0..3 B-slots (u j*64..)
  unsigned int aoff[4], boff[4];
  int swi[4];
  #pragma unroll
  for (int j = 0; j < 4; ++j) {
    const int sw = j * 8 + wid;          // wave-inst slot 0..31
    const int s  = sw * 64 + lane;       // 16B slot 0..2047
    const int r  = s >> 3;               // row 0..255
    const int c  = ((s & 7) - r) & 7;    // source chunk (swizzle)
    aoff[j] = (unsigned int)((m0 + r) * H_SZ + c * 8);
    boff[j] = (unsigned int)(r * H_SZ + c * 8);
    swi[j]  = sw * 512;                  // LDS ushort offset of this wave-inst
  }

  f32x4 acc[8][4];
  float part[8][4];
  #pragma unroll
  for (int rt = 0; rt < 8; ++rt)
    #pragma unroll
    for (int ct = 0; ct < 4; ++ct) {
      part[rt][ct] = 0.0f;
      #pragma unroll
      for (int r = 0; r < 4; ++r) acc[rt][ct][r] = 0.0f;
    }

  float qv[4], vv[4];
  bf16x8 af[4], bfr[4];

  auto STAGE_A = [&](int t, int j) {
    async_cp16(encb + aoff[j] + (unsigned int)(t & 15) * 64u, &Al[t & 1][swi[j]]);
  };
  auto STAGE_B = [&](int t, int j) {
    const unsigned int uo = (unsigned int)((t >> 4) * 256) * H_SZ
                          + (unsigned int)(t & 15) * 64u;
    async_cp16(W2t + uo + boff[j], &Bl[t & 1][swi[j]]);
  };
  auto LDA = [&](const unsigned short* Ab, int rtB, int h) {
    #pragma unroll
    for (int k = 0; k < 4; ++k) {
      const int ar = wr * 128 + (rtB + k) * 16 + l16;
      af[k] = *(const bf16x8*)&Ab[ar * 64 + ((h * 4 + quad + ar) & 7) * 8];
    }
  };
  auto LDB = [&](const unsigned short* Bb, int h) {
    #pragma unroll
    for (int ct = 0; ct < 4; ++ct) {
      const int bu = wc * 64 + ct * 16 + l16;
      bfr[ct] = *(const bf16x8*)&Bb[bu * 64 + ((h * 4 + quad + bu) & 7) * 8];
    }
  };
  auto MFMA16 = [&](int rtB) {
    #pragma unroll
    for (int k = 0; k < 4; ++k)
      #pragma unroll
      for (int ct = 0; ct < 4; ++ct)
        acc[rtB + k][ct] = __builtin_amdgcn_mfma_f32_16x16x32_bf16(
            af[k], bfr[ct], acc[rtB + k][ct], 0, 0, 0);
  };

  // prologue: stage tile 0
  #pragma unroll
  for (int j = 0; j < 4; ++j) STAGE_A(0, j);
  #pragma unroll
  for (int j = 0; j < 4; ++j) STAGE_B(0, j);

  #pragma unroll 2
  for (int i = 0; i < 64; ++i) {
    const unsigned short* Ab = Al[i & 1];
    const unsigned short* Bb = Bl[i & 1];
    const bool pf = (i < 63);

    // tile boundary: wait own tile-i loads, then align all waves
    asm volatile("s_waitcnt vmcnt(0)" ::: "memory");
    __builtin_amdgcn_s_barrier();
    __builtin_amdgcn_sched_barrier(0);

    if ((i & 15) == 0) {   // preload epilogue constants for this ut
      const int u0 = (i >> 4) * 256;
      #pragma unroll
      for (int ct = 0; ct < 4; ++ct) {
        const int u = u0 + wc * 64 + ct * 16 + l16;
        qv[ct] = qq[b * U_SZ + u];
        vv[ct] = Vv[u];
      }
    }

    // ---- phase 0: B[h0] + A[rt0-3,h0] -> 16 MFMA ----
    LDB(Bb, 0);
    LDA(Ab, 0, 0);
    if (pf) { STAGE_A(i + 1, 0); STAGE_A(i + 1, 1); STAGE_A(i + 1, 2); }
    asm volatile("s_waitcnt lgkmcnt(0)" ::: "memory");
    __builtin_amdgcn_sched_barrier(0);
    __builtin_amdgcn_s_setprio(1);
    MFMA16(0);
    __builtin_amdgcn_s_setprio(0);
    __builtin_amdgcn_s_barrier();

    // ---- phase 1: A[rt4-7,h0] -> 16 MFMA ----
    LDA(Ab, 4, 0);
    if (pf) { STAGE_A(i + 1, 3); STAGE_B(i + 1, 0); STAGE_B(i + 1, 1); }
    asm volatile("s_waitcnt lgkmcnt(0)" ::: "memory");
    __builtin_amdgcn_sched_barrier(0);
    __builtin_amdgcn_s_setprio(1);
    MFMA16(4);
    __builtin_amdgcn_s_setprio(0);
    __builtin_amdgcn_s_barrier();

    // ---- phase 2: B[h1] + A[rt0-3,h1] -> 16 MFMA ----
    LDB(Bb, 1);
    LDA(Ab, 0, 1);
    if (pf) { STAGE_B(i + 1, 2); STAGE_B(i + 1, 3); }
    asm volatile("s_waitcnt lgkmcnt(0)" ::: "memory");
    __builtin_amdgcn_sched_barrier(0);
    __builtin_amdgcn_s_setprio(1);
    MFMA16(0);
    __builtin_amdgcn_s_setprio(0);
    __builtin_amdgcn_s_barrier();

    // ---- phase 3: A[rt4-7,h1] -> 16 MFMA ----
    LDA(Ab, 4, 1);
    asm volatile("s_waitcnt lgkmcnt(0)" ::: "memory");
    __builtin_amdgcn_sched_barrier(0);
    __builtin_amdgcn_s_setprio(1);
    MFMA16(4);
    __builtin_amdgcn_s_setprio(0);

    // ut epilogue: fold acc into part via tanh * V
    if ((i & 15) == 15) {
      #pragma unroll
      for (int ct = 0; ct < 4; ++ct)
        #pragma unroll
        for (int rt = 0; rt < 8; ++rt)
          #pragma unroll
          for (int r = 0; r < 4; ++r)
            part[rt][r] += fast_tanh(acc[rt][ct][r] + qv[ct]) * vv[ct];
      #pragma unroll
      for (int rt = 0; rt < 8; ++rt)
        #pragma unroll
        for (int ct = 0; ct < 4; ++ct)
          #pragma unroll
          for (int r = 0; r < 4; ++r) acc[rt][ct][r] = 0.0f;
    }
  }

  // cross-wave score reduce: overlay scoreS on freed Al
  __syncthreads();
  float* scoreS = (float*)&Al[0][0];
  if (tid < BM2) scoreS[tid] = 0.0f;
  __syncthreads();
  #pragma unroll
  for (int rt = 0; rt < 8; ++rt)
    #pragma unroll
    for (int r = 0; r < 4; ++r) {
      float p = part[rt][r];
      p += __shfl_xor(p, 1);
      p += __shfl_xor(p, 2);
      p += __shfl_xor(p, 4);
      p += __shfl_xor(p, 8);
      if (l16 == 0) atomicAdd(&scoreS[wr * 128 + rt * 16 + quad * 4 + r], p);
    }
  __syncthreads();
  if (tid < BM2) score[m0 + tid] = scoreS[tid];
}

// ---------------------------------------------------------------------------
// Fallback GEMM (no-workspace path, fp32 in-kernel convert).
// ---------------------------------------------------------------------------
__global__ __launch_bounds__(256) void k_gemm_score_f32(
    const float* __restrict__ encf,
    const unsigned short* __restrict__ W2t,
    const float* __restrict__ qq, const float* __restrict__ Vv,
    float* __restrict__ score)
{
  __shared__ unsigned short Alo[BM * BK];   // 8 KB
  __shared__ unsigned short Blo[BN * BK];   // 32 KB
  __shared__ float scoreS[BM];

  const int tid  = threadIdx.x;
  const int wave = tid >> 6;
  const int lane = tid & 63;
  const int quad = lane >> 4;
  const int l16  = lane & 15;
  const int m0   = blockIdx.x * BM;
  const int b    = m0 >> 11;

  if (tid < BM) scoreS[tid] = 0.0f;

  size_t boff[8]; unsigned short* dstB[8];
  #pragma unroll
  for (int i = 0; i < 8; ++i) {
    const int slot = (i * 4 + wave) * 64 + lane;
    const int r = slot >> 3;
    const int c = ((slot & 7) - r) & 7;
    boff[i] = (size_t)r * H_SZ + c * 8;
    dstB[i] = &Blo[(i * 4 + wave) * 512];
  }

  const int ar[4] = { 0 * 16 + l16, 1 * 16 + l16, 2 * 16 + l16, 3 * 16 + l16 };
  const int bu[4] = { wave * 64 + 0 * 16 + l16, wave * 64 + 1 * 16 + l16,
                      wave * 64 + 2 * 16 + l16, wave * 64 + 3 * 16 + l16 };

  for (int ut = 0; ut < UT_N; ++ut) {
    const int u0 = ut * BN;
    f32x4 acc[4][4];
    #pragma unroll
    for (int rt = 0; rt < 4; ++rt)
      #pragma unroll
      for (int ct = 0; ct < 4; ++ct)
        #pragma unroll
        for (int r = 0; r < 4; ++r) acc[rt][ct][r] = 0.0f;

    for (int kk = 0; kk < H_SZ; kk += BK) {
      __syncthreads();
      #pragma unroll
      for (int i = 0; i < 2; ++i) {
        const int slot = i * 256 + tid;
        const int r = slot >> 3;
        const int c = ((slot & 7) - r) & 7;
        const float* src = encf + (size_t)(m0 + r) * H_SZ + kk + c * 8;
        const float4 x = *(const float4*)src;
        const float4 y = *(const float4*)(src + 4);
        uint4 o;
        o.x = f2bf(x.x) | (f2bf(x.y) << 16);
        o.y = f2bf(x.z) | (f2bf(x.w) << 16);
        o.z = f2bf(y.x) | (f2bf(y.y) << 16);
        o.w = f2bf(y.z) | (f2bf(y.w) << 16);
        *(uint4*)&Alo[slot * 8] = o;
      }
      #pragma unroll
      for (int i = 0; i < 8; ++i)
        async_cp16(W2t + (size_t)u0 * H_SZ + boff[i] + kk, dstB[i]);
      __syncthreads();

      #pragma unroll
      for (int h = 0; h < 2; ++h) {
        bf16x8 af[4], bfr[4];
        #pragma unroll
        for (int rt = 0; rt < 4; ++rt)
          af[rt] = *(const bf16x8*)&Alo[ar[rt] * 64 + ((h * 4 + quad + ar[rt]) & 7) * 8];
        #pragma unroll
        for (int ct = 0; ct < 4; ++ct)
          bfr[ct] = *(const bf16x8*)&Blo[bu[ct] * 64 + ((h * 4 + quad + bu[ct]) & 7) * 8];
        #pragma unroll
        for (int rt = 0; rt < 4; ++rt)
          #pragma unroll
          for (int ct = 0; ct < 4; ++ct)
            acc[rt][ct] = __builtin_amdgcn_mfma_f32_16x16x32_bf16(
                af[rt], bfr[ct], acc[rt][ct], 0, 0, 0);
      }
    }

    float part[4][4];
    #pragma unroll
    for (int rt = 0; rt < 4; ++rt)
      #pragma unroll
      for (int r = 0; r < 4; ++r) part[rt][r] = 0.0f;
    #pragma unroll
    for (int ct = 0; ct < 4; ++ct) {
      const int u = u0 + wave * 64 + ct * 16 + l16;
      const float qvs = qq[b * U_SZ + u];
      const float vvs = Vv[u];
      #pragma unroll
      for (int rt = 0; rt < 4; ++rt)
        #pragma unroll
        for (int r = 0; r < 4; ++r)
          part[rt][r] += fast_tanh(acc[rt][ct][r] + qvs) * vvs;
    }
    #pragma unroll
    for (int rt = 0; rt < 4; ++rt)
      #pragma unroll
      for (int r = 0; r < 4; ++r) {
        float p = part[rt][r];
        p += __shfl_xor(p, 1);
        p += __shfl_xor(p, 2);
        p += __shfl_xor(p, 4);
        p += __shfl_xor(p, 8);
        part[rt][r] = p;
      }
    if (l16 == 0) {
      #pragma unroll
      for (int rt = 0; rt < 4; ++rt)
        #pragma unroll
        for (int r = 0; r < 4; ++r)
          atomicAdd(&scoreS[rt * 16 + quad * 4 + r], part[rt][r]);
    }
  }
  __syncthreads();
  if (tid < BM) score[m0 + tid] = scoreS[tid];
}

// ---------------------------------------------------------------------------
// softmax over T per batch (fallback path; bv dropped: softmax-invariant)
// ---------------------------------------------------------------------------
__global__ void k_softmax(const float* __restrict__ score, float* __restrict__ attn) {
  const int b = blockIdx.x;
  const int tid = threadIdx.x;   // 256
  __shared__ float wmax[4], wsum[4];
  const float* s = score + b * T_SZ;
  float v[8];
  float lmax = -INFINITY;
  #pragma unroll
  for (int i = 0; i < 8; ++i) { v[i] = s[tid + i * 256]; lmax = fmaxf(lmax, v[i]); }
  #pragma unroll
  for (int m = 1; m <= 32; m <<= 1) lmax = fmaxf(lmax, __shfl_xor(lmax, m));
  if ((tid & 63) == 0) wmax[tid >> 6] = lmax;
  __syncthreads();
  const float gmax = fmaxf(fmaxf(wmax[0], wmax[1]), fmaxf(wmax[2], wmax[3]));
  float lsum = 0.0f;
  #pragma unroll
  for (int i = 0; i < 8; ++i) { v[i] = __expf(v[i] - gmax); lsum += v[i]; }
  #pragma unroll
  for (int m = 1; m <= 32; m <<= 1) lsum += __shfl_xor(lsum, m);
  if ((tid & 63) == 0) wsum[tid >> 6] = lsum;
  __syncthreads();
  const float inv = 1.0f / (wsum[0] + wsum[1] + wsum[2] + wsum[3]);
  #pragma unroll
  for (int i = 0; i < 8; ++i) attn[b * T_SZ + tid + i * 256] = v[i] * inv;
}

// ---------------------------------------------------------------------------
// Fused softmax + context (fast path): each (tcx,hc,b) block recomputes the
// row softmax from score (8 KB, L2-hot), stages its 256 attn values in LDS,
// hc==0 writes the attn output slice; then the context partial as before.
// Removes the k_softmax dispatch + attn global round-trip.
// ---------------------------------------------------------------------------
__global__ __launch_bounds__(256) void k_ctx_sm(
    const unsigned short* __restrict__ encb,
    const float* __restrict__ score,
    float* __restrict__ attn, float* __restrict__ ctx)
{
  const int tcx = blockIdx.x;   // 0..7
  const int hc  = blockIdx.y;   // 0..1
  const int b   = blockIdx.z;   // 0..31
  const int tid = threadIdx.x;  // 256
  __shared__ float wmax[4], wsum[4];
  __shared__ float att_l[256];

  const float* s = score + b * T_SZ;
  float v[8];
  float lmax = -INFINITY;
  #pragma unroll
  for (int i = 0; i < 8; ++i) { v[i] = s[tid + i * 256]; lmax = fmaxf(lmax, v[i]); }
  #pragma unroll
  for (int m = 1; m <= 32; m <<= 1) lmax = fmaxf(lmax, __shfl_xor(lmax, m));
  if ((tid & 63) == 0) wmax[tid >> 6] = lmax;
  __syncthreads();
  const float gmax = fmaxf(fmaxf(wmax[0], wmax[1]), fmaxf(wmax[2], wmax[3]));
  float lsum = 0.0f;
  #pragma unroll
  for (int i = 0; i < 8; ++i) { v[i] = __expf(v[i] - gmax); lsum += v[i]; }
  #pragma unroll
  for (int m = 1; m <= 32; m <<= 1) lsum += __shfl_xor(lsum, m);
  if ((tid & 63) == 0) wsum[tid >> 6] = lsum;
  __syncthreads();
  const float inv = 1.0f / (wsum[0] + wsum[1] + wsum[2] + wsum[3]);

  // this block's attn slice: t = tcx*256 + tid  (recompute, avoid v[tcx] dyn-idx)
  const float av = __expf(s[tcx * 256 + tid] - gmax) * inv;
  att_l[tid] = av;
  if (hc == 0) attn[b * T_SZ + tcx * 256 + tid] = av;
  __syncthreads();

  const int h0 = hc * 512 + tid * 2;
  const unsigned short* e = encb + ((size_t)b * T_SZ + tcx * 256) * H_SZ + h0;
  float c0 = 0, c1 = 0;
  #pragma unroll 4
  for (int t = 0; t < 256; ++t) {
    const unsigned int w = *(const unsigned int*)&e[(size_t)t * H_SZ];
    c0 += att_l[t] * bf2f(w & 0xFFFFu);
    c1 += att_l[t] * bf2f(w >> 16);
  }
  atomicAdd(&ctx[b * H_SZ + h0],     c0);
  atomicAdd(&ctx[b * H_SZ + h0 + 1], c1);
}

__global__ void k_context_f32(const float* __restrict__ enc,
                              const float* __restrict__ attn, float* __restrict__ ctx) {
  const int tcx = blockIdx.x, hc = blockIdx.y, b = blockIdx.z;
  const int h = hc * 256 + threadIdx.x;
  const float* e = enc + ((size_t)b * T_SZ + tcx * 256) * H_SZ + h;
  const float* a = attn + b * T_SZ + tcx * 256;
  float a0 = 0, a1 = 0, a2 = 0, a3 = 0;
  for (int t = 0; t < 256; t += 4) {
    a0 += a[t]     * e[(size_t)t * H_SZ];
    a1 += a[t + 1] * e[(size_t)(t + 1) * H_SZ];
    a2 += a[t + 2] * e[(size_t)(t + 2) * H_SZ];
    a3 += a[t + 3] * e[(size_t)(t + 3) * H_SZ];
  }
  atomicAdd(&ctx[b * H_SZ + h], (a0 + a1) + (a2 + a3));
}

// ---------------------------------------------------------------------------
extern "C" void kernel_launch(void* const* d_in, const int* in_sizes, int n_in,
                              void* d_out, int out_size, void* d_ws, size_t ws_size,
                              hipStream_t stream) {
  const float* dec = (const float*)d_in[0];
  const float* enc = (const float*)d_in[1];
  const float* W1  = (const float*)d_in[2];
  const float* b1  = (const float*)d_in[3];
  const float* W2  = (const float*)d_in[4];
  const float* b2  = (const float*)d_in[5];
  const float* Vv  = (const float*)d_in[6];
  // d_in[7] = bv: constant shift inside softmax -> no effect on outputs.

  const size_t encb_bytes = (size_t)B_SZ * T_SZ * H_SZ * 2;   // 128 MB
  const size_t fast_need  = encb_bytes + (2u << 20) + (128u << 10) + (256u << 10);
  const bool fast = ws_size >= fast_need;

  char* ws = (char*)d_ws;
  unsigned short* encb = nullptr;
  unsigned short* W2t;
  float *qq, *score;
  if (fast) {
    encb  = (unsigned short*)ws;
    W2t   = (unsigned short*)(ws + encb_bytes);
    qq    = (float*)(ws + encb_bytes + (2u << 20));
    score = (float*)(ws + encb_bytes + (2u << 20) + (128u << 10));
  } else {
    W2t   = (unsigned short*)ws;
    qq    = (float*)(ws + (2u << 20));
    score = (float*)(ws + (2u << 20) + (128u << 10));
  }

  float* ctx  = (float*)d_out;                  // [32,1024]
  float* attn = (float*)d_out + B_SZ * H_SZ;    // [32,2048,1]

  hipMemsetAsync(ctx, 0, B_SZ * H_SZ * sizeof(float), stream);
  const int cvtN = fast ? (B_SZ * T_SZ * H_SZ) / (256 * 8) : 0;   // 2048 or 0
  k_prep<<<cvtN + 256 + 512, 256, 0, stream>>>(enc, encb, W2, W2t,
                                               dec, W1, b1, b2, qq, cvtN);
  if (fast) {
    k_gemm_score2<<<(B_SZ * T_SZ) / BM2, 512, 0, stream>>>(encb, W2t, qq, Vv, score);
    k_ctx_sm<<<dim3(8, 2, 32), 256, 0, stream>>>(encb, score, attn, ctx);
  } else {
    k_gemm_score_f32<<<(B_SZ * T_SZ) / BM, 256, 0, stream>>>(enc, W2t, qq, Vv, score);
    k_softmax<<<32, 256, 0, stream>>>(score, attn);
    k_context_f32<<<dim3(8, 4, 32), 256, 0, stream>>>(enc, attn, ctx);
  }
}